// Round 6
// baseline (1878.093 us; speedup 1.0000x reference)
//
#include <hip/hip_runtime.h>
#include <cstdio>
#include <cstdint>

// PointNet++ SA module, MI355X. Recompute pipeline; layers 2/3 on MFMA (bf16).
// B=16, N=4096, M=1024; scale0: r=0.1,K=32,[67,64,64,128]; scale1: r=0.2,K=64,[67,64,96,128]

constexpr int BATCH = 16, NPTS = 4096, MCTR = 1024;
constexpr int BM = BATCH * MCTR;   // 16384 centers
constexpr int NSLOT = 32;          // stats contention-spreading slots

typedef short bf16x8 __attribute__((ext_vector_type(8)));
typedef float f32x4  __attribute__((ext_vector_type(4)));

__device__ __forceinline__ ushort f2bf(float f) {
  uint32_t u = __float_as_uint(f);
  u += 0x7fffu + ((u >> 16) & 1u);   // RNE
  return (ushort)(u >> 16);
}
__device__ __forceinline__ uint32_t packbf(float a, float b) {
  return (uint32_t)f2bf(a) | ((uint32_t)f2bf(b) << 16);
}
__device__ __forceinline__ unsigned long long umax64(unsigned long long a,
                                                     unsigned long long b) {
  return (a > b) ? a : b;
}

// ---------------- farthest point sampling ----------------
// One block (512 thr) per batch, 8 pts/thread. Butterfly only over DPP-friendly
// offsets 1..8; 32 group-winner keys to LDS; one barrier/iter (parity dbuf);
// vectorized key readback + max tree. Distance arithmetic bit-exact vs ref.
__global__ __launch_bounds__(512) void fps_kernel(const float* __restrict__ pc,
                                                  int* __restrict__ samp) {
  int b = blockIdx.x, t = threadIdx.x;
  int lane = t & 63, w = t >> 6;
  const float* px = pc + (size_t)b * 3 * NPTS;
  __shared__ float lX[NPTS], lY[NPTS], lZ[NPTS];
  __shared__ __align__(16) unsigned long long wkey[2][32];
  float X[8], Y[8], Z[8], D[8];
#pragma unroll
  for (int j = 0; j < 8; j++) {
    int p = t + 512 * j;
    float x = px[p], y = px[NPTS + p], z = px[2 * NPTS + p];
    X[j] = x; Y[j] = y; Z[j] = z; D[j] = 1e10f;
    lX[p] = x; lY[p] = y; lZ[p] = z;
  }
  __syncthreads();
  if (t == 0) samp[b * MCTR] = 0;
  int far = 0;
  for (int it = 1; it < MCTR; it++) {
    float cx = lX[far], cy = lY[far], cz = lZ[far];
    float bv = -1.0f; int bi = 0;
#pragma unroll
    for (int j = 0; j < 8; j++) {
      float dx = __fsub_rn(X[j], cx), dy = __fsub_rn(Y[j], cy), dz = __fsub_rn(Z[j], cz);
      float d = __fadd_rn(__fadd_rn(__fmul_rn(dx, dx), __fmul_rn(dy, dy)), __fmul_rn(dz, dz));
      float dm = fminf(D[j], d);
      D[j] = dm;
      bool g = dm > bv;               // ascending j => first-index within thread
      bv = g ? dm : bv; bi = g ? t + 512 * j : bi;
    }
    // dm >= 0 always => sign bit clear => uint order == float order
    unsigned long long key =
        ((unsigned long long)__float_as_uint(bv) << 32) | (unsigned)(~bi);
#pragma unroll
    for (int off = 1; off <= 8; off <<= 1)
      key = umax64(key, (unsigned long long)__shfl_xor(key, off));
    if ((lane & 15) == 0) wkey[it & 1][w * 4 + (lane >> 4)] = key;
    __syncthreads();
    const unsigned long long* kp = wkey[it & 1];
    unsigned long long kk[16];
#pragma unroll
    for (int i = 0; i < 16; i++) kk[i] = umax64(kp[2 * i], kp[2 * i + 1]);
#pragma unroll
    for (int s = 8; s; s >>= 1)
#pragma unroll
      for (int i = 0; i < s; i++) kk[i] = umax64(kk[i], kk[i + s]);
    far = (int)(~(unsigned)kk[0]);
    if (t == 0) samp[b * MCTR + it] = far;
  }
}

// ---------------- gather sampled centers into d_out (B,3,M) ----------------
__global__ __launch_bounds__(256) void newpc_kernel(const float* __restrict__ pc,
                                                    const int* __restrict__ samp,
                                                    float* __restrict__ out) {
  int i = blockIdx.x * 256 + threadIdx.x;
  int m = i & 1023;
  int c = (i >> 10) % 3;
  int b = i / 3072;
  out[i] = pc[((size_t)b * 3 + c) * NPTS + samp[b * MCTR + m]];
}

// ---------------- ball query: wave per center, ballot-ranked first-K ----------------
template <int K>
__global__ __launch_bounds__(256) void ballq_kernel(const float* __restrict__ pc,
                                                    const float* __restrict__ newpc,
                                                    int* __restrict__ gidx, float r2) {
  int lane = threadIdx.x & 63;
  int wave = threadIdx.x >> 6;
  int center = blockIdx.x * 4 + wave;
  int b = center >> 10, m = center & 1023;
  const float* nb = newpc + (size_t)b * 3 * MCTR + m;
  float cx = nb[0], cy = nb[MCTR], cz = nb[2 * MCTR];
  const float* px = pc + (size_t)b * 3 * NPTS;
  int cnt = 0;
  int firstn = 0x7fffffff;
  for (int chunk = 0; chunk < NPTS / 64 && cnt < K; chunk++) {
    int n = chunk * 64 + lane;
    float dx = __fsub_rn(cx, px[n]);
    float dy = __fsub_rn(cy, px[NPTS + n]);
    float dz = __fsub_rn(cz, px[2 * NPTS + n]);
    float d2 = __fadd_rn(__fadd_rn(__fmul_rn(dx, dx), __fmul_rn(dy, dy)), __fmul_rn(dz, dz));
    bool in = d2 < r2;
    unsigned long long ball = __ballot(in);
    int pos = cnt + (int)__popcll(ball & ((1ull << lane) - 1ull));
    if (in && pos < K) gidx[(size_t)center * K + pos] = n;
    if (in && pos == 0) firstn = n;
    cnt += (int)__popcll(ball);
  }
#pragma unroll
  for (int off = 32; off; off >>= 1) firstn = min(firstn, __shfl_xor(firstn, off));
  if (lane < K && lane >= cnt) gidx[(size_t)center * K + lane] = firstn;
}

// ---------------- fp32 weight transposes (u_kernel / layer1 xyz) ----------------
__global__ __launch_bounds__(256) void prep_kernel(const float* __restrict__ W00,
                                                   const float* __restrict__ W01,
                                                   const float* __restrict__ W02,
                                                   const float* __restrict__ W10,
                                                   const float* __restrict__ W11,
                                                   const float* __restrict__ W12,
                                                   float* __restrict__ wt) {
  int e = blockIdx.x * 256 + threadIdx.x;
  if (e < 4096) { wt[e] = W00[(e & 63) * 67 + 3 + (e >> 6)]; return; }
  e -= 4096;
  if (e < 192)  { wt[4096 + e] = W00[(e & 63) * 67 + (e >> 6)]; return; }
  e -= 192;
  if (e < 4096) { wt[16576 + e] = W10[(e & 63) * 67 + 3 + (e >> 6)]; return; }
  e -= 4096;
  if (e < 192)  { wt[20672 + e] = W10[(e & 63) * 67 + (e >> 6)]; return; }
  (void)W01; (void)W02; (void)W11; (void)W12;
}

// ---------------- bf16 A-fragment weight packing for MFMA ----------------
// wf (ushort): W2f0@0(4096) W3f0@4096(8192) W2f1@12288(6144) W3f1@18432(12288)
// Frag order: ((kc*MT + mt)*64 + lane)*8 + j ; A[m=lane&15][k=(lane>>4)*8+j]
__global__ __launch_bounds__(256) void prep_frag(const float* __restrict__ W01,
                                                 const float* __restrict__ W02,
                                                 const float* __restrict__ W11,
                                                 const float* __restrict__ W12,
                                                 ushort* __restrict__ wf) {
  int e = blockIdx.x * 256 + threadIdx.x;   // < 30720
  const float* W; int CIN, MT, off;
  if (e < 4096)       { W = W01; CIN = 64; MT = 4; off = 0; }
  else if (e < 12288) { W = W02; CIN = 64; MT = 8; off = 4096; }
  else if (e < 18432) { W = W11; CIN = 64; MT = 6; off = 12288; }
  else                { W = W12; CIN = 96; MT = 8; off = 18432; }
  int r = e - off;
  int j = r & 7, lane = (r >> 3) & 63, fm = r >> 9;
  int kc = fm / MT, mt = fm % MT;
  int out_ch = mt * 16 + (lane & 15);
  int in_ch  = kc * 32 + (lane >> 4) * 8 + j;
  wf[e] = f2bf(W[out_ch * CIN + in_ch]);
}

// ---------------- U = W_feat . feat + b1, layout [b][n][64] ----------------
__global__ __launch_bounds__(256) void u_kernel(const float* __restrict__ feat,
                                                const float* __restrict__ WtF,
                                                const float* __restrict__ b1,
                                                float* __restrict__ U) {
  int gid = blockIdx.x * 256 + threadIdx.x;
  int b = gid >> 12, n = gid & 4095;
  float acc[64];
#pragma unroll
  for (int o = 0; o < 64; o++) acc[o] = b1[o];
  const float* fb = feat + (size_t)b * 64 * NPTS + n;
  for (int c = 0; c < 64; c++) {
    float x = fb[(size_t)c * NPTS];
    const float* wc = WtF + c * 64;
#pragma unroll
    for (int o = 0; o < 64; o++) acc[o] = fmaf(wc[o], x, acc[o]);
  }
  float4* u4 = (float4*)(U + (size_t)gid * 64);
#pragma unroll
  for (int q = 0; q < 16; q++) u4[q] = make_float4(acc[4*q], acc[4*q+1], acc[4*q+2], acc[4*q+3]);
}

// ---------------- layer-1 stats pass (VALU; cheap) ----------------
template <int K, bool MM>
__device__ __forceinline__ void wave_reduce32(const float* vals, float* tile, int t,
                                              int center0, float* swrow, int co,
                                              float* maxbuf, float* minbuf) {
  float* myrow = tile + t * 32;
  int rsw = t & 31;
#pragma unroll
  for (int o = 0; o < 32; o++) myrow[o ^ rsw] = vals[o];
  __syncthreads();
  int lane = t & 63;
  int ch = lane & 31, sub = lane >> 5;
  const float* base = tile + (t & ~63) * 32;
  float s = 0.f, s2 = 0.f;
#pragma unroll
  for (int r = 0; r < 32; r++) {
    int row = sub * 32 + r;
    float v = base[row * 32 + (ch ^ (row & 31))];
    s += v; s2 = fmaf(v, v, s2);
  }
  float st = s + __shfl_xor(s, 32);
  float st2 = s2 + __shfl_xor(s2, 32);
  if (sub == 0) {
    swrow[co + ch] += st;
    swrow[128 + co + ch] += st2;
  }
  (void)center0; (void)maxbuf; (void)minbuf;
  __syncthreads();
}

template <int K>
__global__ __launch_bounds__(128, 2) void l1_pass(
    const float* __restrict__ U, const float* __restrict__ pc,
    const float* __restrict__ newpc, const int* __restrict__ gidx,
    const float* __restrict__ Wt1, float* __restrict__ stats) {
  __shared__ float tile[128 * 32];
  __shared__ float sAccW[2][256];
  const int t = threadIdx.x;
  const int w = t >> 6;
  const int p = blockIdx.x * 128 + t;
  const int bm = p / K;
  const int b = bm >> 10, m = bm & 1023;
  const int idx = gidx[p];
  for (int i = t; i < 512; i += 128) ((float*)sAccW)[i] = 0.f;

  float dx = pc[((size_t)b * 3 + 0) * NPTS + idx] - newpc[((size_t)b * 3 + 0) * MCTR + m];
  float dy = pc[((size_t)b * 3 + 1) * NPTS + idx] - newpc[((size_t)b * 3 + 1) * MCTR + m];
  float dz = pc[((size_t)b * 3 + 2) * NPTS + idx] - newpc[((size_t)b * 3 + 2) * MCTR + m];
  float v1[64];
  const float4* u4 = (const float4*)(U + (size_t)((b << 12) + idx) * 64);
#pragma unroll
  for (int qq = 0; qq < 16; qq++) {
    float4 u = u4[qq];
    v1[4*qq] = u.x; v1[4*qq+1] = u.y; v1[4*qq+2] = u.z; v1[4*qq+3] = u.w;
  }
#pragma unroll
  for (int o = 0; o < 64; o++) v1[o] = fmaf(Wt1[o], dx, v1[o]);
#pragma unroll
  for (int o = 0; o < 64; o++) v1[o] = fmaf(Wt1[64 + o], dy, v1[o]);
#pragma unroll
  for (int o = 0; o < 64; o++) v1[o] = fmaf(Wt1[128 + o], dz, v1[o]);

  wave_reduce32<K, false>(v1,      tile, t, 0, sAccW[w], 0,  nullptr, nullptr);
  wave_reduce32<K, false>(v1 + 32, tile, t, 0, sAccW[w], 32, nullptr, nullptr);

  __syncthreads();
  float* dst = stats + (size_t)(blockIdx.x & (NSLOT - 1)) * 128;
  for (int i = t; i < 64; i += 128) {
    atomicAdd(&dst[i],      sAccW[0][i]       + sAccW[1][i]);
    atomicAdd(&dst[64 + i], sAccW[0][128 + i] + sAccW[1][128 + i]);
  }
}

// ---------------- MFMA MLP pass: layer1 (VALU) -> layer2[/3] (MFMA) ----------------
// NL=2: stats of pre-BN layer2.  NL=3: stats of pre-BN layer3 + per-center max/min.
// All LDS regions are per-wave: no block barrier until the final stats flush.
template <int K, int C2, int NL>
__global__ __launch_bounds__(256, 2) void mfma_pass(
    const float* __restrict__ U, const float* __restrict__ pc,
    const float* __restrict__ newpc, const int* __restrict__ gidx,
    const float* __restrict__ Wt1,
    const ushort* __restrict__ W2f, const ushort* __restrict__ W3f,
    const float* __restrict__ b2, const float* __restrict__ b3,
    const float* __restrict__ cA1, const float* __restrict__ cC1,
    const float* __restrict__ cA2, const float* __restrict__ cC2,
    float* __restrict__ stats, float* __restrict__ maxbuf, float* __restrict__ minbuf) {
  constexpr int MT2 = C2 / 16, KC3 = C2 / 32;
  constexpr int CLs = (NL == 2) ? C2 : 128;
  constexpr int SSTR = CLs + 4;                       // scratch row stride (ushorts)
  __shared__ __align__(16) ushort x1f[4][2][4][64][8];         // 32 KB, B-frag order
  __shared__ __align__(16) ushort x2f[(NL == 3) ? 4 : 1][KC3][4][16][8];
  __shared__ __align__(16) ushort x3s[4][16][SSTR];            // pre-BN scratch rows
  __shared__ float sAccW[4][256];

  const int t = threadIdx.x, w = t >> 6, lane = t & 63;
  const int q = lane >> 4, n = lane & 15;
  const int p = blockIdx.x * 256 + t;
  const int bm = p / K;
  const int b = bm >> 10, m = bm & 1023;
  const int idx = gidx[p];

  // ---- layer1 per-thread (position = t) ----
  float dx = pc[((size_t)b * 3 + 0) * NPTS + idx] - newpc[((size_t)b * 3 + 0) * MCTR + m];
  float dy = pc[((size_t)b * 3 + 1) * NPTS + idx] - newpc[((size_t)b * 3 + 1) * MCTR + m];
  float dz = pc[((size_t)b * 3 + 2) * NPTS + idx] - newpc[((size_t)b * 3 + 2) * MCTR + m];
  {
    float v1[64];
    const float4* u4 = (const float4*)(U + (size_t)((b << 12) + idx) * 64);
#pragma unroll
    for (int qq = 0; qq < 16; qq++) {
      float4 u = u4[qq];
      v1[4*qq] = u.x; v1[4*qq+1] = u.y; v1[4*qq+2] = u.z; v1[4*qq+3] = u.w;
    }
#pragma unroll
    for (int o = 0; o < 64; o++) v1[o] = fmaf(Wt1[o], dx, v1[o]);
#pragma unroll
    for (int o = 0; o < 64; o++) v1[o] = fmaf(Wt1[64 + o], dy, v1[o]);
#pragma unroll
    for (int o = 0; o < 64; o++) v1[o] = fmaf(Wt1[128 + o], dz, v1[o]);
    // bn1relu -> x1f B-frag rows (ch = kc*32 + q*8 + j), own 16B slot per thread
    int nw = t & 63;
#pragma unroll
    for (int g = 0; g < 8; g++) {
      uint32_t d0, d1, d2, d3;
      int c = g * 8;
      d0 = packbf(fmaxf(0.f, fmaf(cA1[c+0], v1[c+0], cC1[c+0])),
                  fmaxf(0.f, fmaf(cA1[c+1], v1[c+1], cC1[c+1])));
      d1 = packbf(fmaxf(0.f, fmaf(cA1[c+2], v1[c+2], cC1[c+2])),
                  fmaxf(0.f, fmaf(cA1[c+3], v1[c+3], cC1[c+3])));
      d2 = packbf(fmaxf(0.f, fmaf(cA1[c+4], v1[c+4], cC1[c+4])),
                  fmaxf(0.f, fmaf(cA1[c+5], v1[c+5], cC1[c+5])));
      d3 = packbf(fmaxf(0.f, fmaf(cA1[c+6], v1[c+6], cC1[c+6])),
                  fmaxf(0.f, fmaf(cA1[c+7], v1[c+7], cC1[c+7])));
      *(uint4*)&x1f[w][g >> 2][g & 3][nw][0] = make_uint4(d0, d1, d2, d3);
    }
  }
  asm volatile("s_waitcnt lgkmcnt(0)" ::: "memory");

  // ---- preload A-fragments into registers ----
  bf16x8 A2[2 * MT2];
#pragma unroll
  for (int i = 0; i < 2 * MT2; i++) A2[i] = *(const bf16x8*)(W2f + (i * 64 + lane) * 8);
  bf16x8 A3[(NL == 3) ? KC3 * 8 : 1];
  if (NL == 3) {
#pragma unroll
    for (int i = 0; i < KC3 * 8; i++) A3[i] = *(const bf16x8*)(W3f + (i * 64 + lane) * 8);
  }

  float sS0 = 0.f, sS1 = 0.f, sS20 = 0.f, sS21 = 0.f;
  float mx0 = -3.4e38f, mx1 = -3.4e38f, mn0 = 3.4e38f, mn1 = 3.4e38f;

#pragma unroll
  for (int tl = 0; tl < 4; tl++) {
    // layer2 MFMA
    bf16x8 bf2[2];
#pragma unroll
    for (int kc = 0; kc < 2; kc++)
      bf2[kc] = *(const bf16x8*)&x1f[w][kc][q][tl * 16 + n][0];
    f32x4 acc2[MT2];
#pragma unroll
    for (int mt = 0; mt < MT2; mt++) acc2[mt] = *(const f32x4*)(b2 + mt * 16 + q * 4);
#pragma unroll
    for (int kc = 0; kc < 2; kc++)
#pragma unroll
      for (int mt = 0; mt < MT2; mt++)
        acc2[mt] = __builtin_amdgcn_mfma_f32_16x16x32_bf16(A2[kc * MT2 + mt], bf2[kc],
                                                           acc2[mt], 0, 0, 0);
    if (NL == 2) {
      // pre-BN layer2 -> scratch
#pragma unroll
      for (int mt = 0; mt < MT2; mt++) {
        int ch0 = mt * 16 + q * 4;
        *(uint2*)&x3s[w][n][ch0] = make_uint2(packbf(acc2[mt][0], acc2[mt][1]),
                                              packbf(acc2[mt][2], acc2[mt][3]));
      }
    } else {
      // bn2relu -> x2f B-frag rows
#pragma unroll
      for (int mt = 0; mt < MT2; mt++) {
        int ch0 = mt * 16 + q * 4;
        f32x4 ca = *(const f32x4*)(cA2 + ch0);
        f32x4 cc = *(const f32x4*)(cC2 + ch0);
        float r0 = fmaxf(0.f, fmaf(ca[0], acc2[mt][0], cc[0]));
        float r1 = fmaxf(0.f, fmaf(ca[1], acc2[mt][1], cc[1]));
        float r2 = fmaxf(0.f, fmaf(ca[2], acc2[mt][2], cc[2]));
        float r3 = fmaxf(0.f, fmaf(ca[3], acc2[mt][3], cc[3]));
        int kc2 = ch0 >> 5, q2 = (ch0 >> 3) & 3, j0 = ch0 & 7;
        *(uint2*)&x2f[w][kc2][q2][n][j0] = make_uint2(packbf(r0, r1), packbf(r2, r3));
      }
      asm volatile("s_waitcnt lgkmcnt(0)" ::: "memory");
      // layer3 MFMA
      f32x4 acc3[8];
#pragma unroll
      for (int mt = 0; mt < 8; mt++) acc3[mt] = *(const f32x4*)(b3 + mt * 16 + q * 4);
#pragma unroll
      for (int kc = 0; kc < KC3; kc++) {
        bf16x8 bf3 = *(const bf16x8*)&x2f[w][kc][q][n][0];
#pragma unroll
        for (int mt = 0; mt < 8; mt++)
          acc3[mt] = __builtin_amdgcn_mfma_f32_16x16x32_bf16(A3[kc * 8 + mt], bf3,
                                                             acc3[mt], 0, 0, 0);
      }
      // pre-BN layer3 -> scratch
#pragma unroll
      for (int mt = 0; mt < 8; mt++) {
        int ch0 = mt * 16 + q * 4;
        *(uint2*)&x3s[w][n][ch0] = make_uint2(packbf(acc3[mt][0], acc3[mt][1]),
                                              packbf(acc3[mt][2], acc3[mt][3]));
      }
    }
    asm volatile("s_waitcnt lgkmcnt(0)" ::: "memory");
    // readback reduce: this lane owns channels (2*lane, 2*lane+1)
    if (2 * lane < CLs) {
#pragma unroll
      for (int pos = 0; pos < 16; pos++) {
        uint32_t u = *(const uint32_t*)&x3s[w][pos][2 * lane];
        float v0 = __uint_as_float(u << 16);
        float v1v = __uint_as_float(u & 0xffff0000u);
        sS0 += v0;  sS20 = fmaf(v0, v0, sS20);
        sS1 += v1v; sS21 = fmaf(v1v, v1v, sS21);
        if (NL == 3) {
          mx0 = fmaxf(mx0, v0);  mn0 = fminf(mn0, v0);
          mx1 = fmaxf(mx1, v1v); mn1 = fminf(mn1, v1v);
        }
      }
    }
    if (NL == 3) {
      bool fl = (K == 64) ? (tl == 3) : ((tl & 1) == 1);
      if (fl) {
        int center = (K == 64) ? (blockIdx.x * 4 + w)
                               : (blockIdx.x * 8 + w * 2 + (tl >> 1));
        *(float2*)&maxbuf[(size_t)center * 128 + 2 * lane] = make_float2(mx0, mx1);
        *(float2*)&minbuf[(size_t)center * 128 + 2 * lane] = make_float2(mn0, mn1);
        mx0 = mx1 = -3.4e38f; mn0 = mn1 = 3.4e38f;
      }
    }
    asm volatile("s_waitcnt lgkmcnt(0)" ::: "memory");   // scratch reuse next tl
  }

  // ---- stats: per-wave LDS row, then one slotted flush per block ----
  {
    int ch = 2 * lane;
    if (ch < CLs) {
      sAccW[w][ch] = sS0;        sAccW[w][ch + 1] = sS1;
      sAccW[w][CLs + ch] = sS20; sAccW[w][CLs + ch + 1] = sS21;
    }
  }
  __syncthreads();
  float* dst = stats + (size_t)(blockIdx.x & (NSLOT - 1)) * (2 * CLs);
  for (int i = t; i < 2 * CLs; i += 256)
    atomicAdd(&dst[i], sAccW[0][i] + sAccW[1][i] + sAccW[2][i] + sAccW[3][i]);
}

// ---------------- BN coeffs from slotted stats ----------------
__global__ void finalize_kernel(const float* __restrict__ stats, const float* __restrict__ g,
                                const float* __restrict__ be, float invP,
                                float* __restrict__ cA, float* __restrict__ cC, int C) {
  int t = threadIdx.x;
  if (t < C) {
    float s = 0.f, s2 = 0.f;
    for (int sl = 0; sl < NSLOT; sl++) {
      s  += stats[sl * 2 * C + t];
      s2 += stats[sl * 2 * C + C + t];
    }
    float mu = s * invP;
    float var = fmaf(s2, invP, -(mu * mu));
    float a = g[t] / sqrtf(var + 1e-5f);
    cA[t] = a;
    cC[t] = fmaf(-a, mu, be[t]);
  }
}

// ---------------- final output: affine(max/min by sign) + relu, transposed write ----------------
__global__ __launch_bounds__(256) void outwrite_kernel(const float* __restrict__ maxbuf,
                                                       const float* __restrict__ minbuf,
                                                       const float* __restrict__ cA3,
                                                       const float* __restrict__ cC3,
                                                       float* __restrict__ out_feat, int chOff) {
  __shared__ float tile[64 * 130];
  int c0 = blockIdx.x * 64;
  int t = threadIdx.x;
#pragma unroll
  for (int i = 0; i < 32; i++) {
    int e = i * 256 + t;
    int lc = e >> 7, o = e & 127;
    float a = cA3[o];
    float v = (a >= 0.f) ? fmaf(a, maxbuf[(size_t)(c0 + lc) * 128 + o], cC3[o])
                         : fmaf(a, minbuf[(size_t)(c0 + lc) * 128 + o], cC3[o]);
    tile[lc * 130 + o] = fmaxf(v, 0.f);
  }
  __syncthreads();
  int b = c0 >> 10, m0 = c0 & 1023;
#pragma unroll
  for (int j = 0; j < 32; j++) {
    int e = j * 256 + t;
    int lm = e & 63, o = e >> 6;
    out_feat[((size_t)(b * 256 + chOff + o)) * MCTR + m0 + lm] = tile[lm * 130 + o];
  }
}

// ======================= host launch =======================
extern "C" void kernel_launch(void* const* d_in, const int* in_sizes, int n_in,
                              void* d_out, int out_size, void* d_ws, size_t ws_size,
                              hipStream_t stream) {
  (void)in_sizes; (void)n_in; (void)out_size;
  const float* pc   = (const float*)d_in[0];
  const float* feat = (const float*)d_in[1];
  const float *Wp[2][3], *bp[2][3], *gp[2][3], *bep[2][3];
  for (int s = 0; s < 2; s++)
    for (int l = 0; l < 3; l++) {
      int base = 2 + (s * 3 + l) * 4;
      Wp[s][l]  = (const float*)d_in[base + 0];
      bp[s][l]  = (const float*)d_in[base + 1];
      gp[s][l]  = (const float*)d_in[base + 2];
      bep[s][l] = (const float*)d_in[base + 3];
    }

  char* ws = (char*)d_ws;
  int*    samp    = (int*)   (ws + 0x0);         // 64 KB
  float*  statsR  = (float*) (ws + 0x10000);     // 6 x NSLOT x 256 f32 = 192 KB
  float*  coef    = (float*) (ws + 0xD0000);
  ushort* wf      = (ushort*)(ws + 0xD2000);     // 60 KB bf16 A-frags
  float*  wt      = (float*) (ws + 0xE2000);     // fp32 transposed weights
  float*  U       = (float*) (ws + 0x110000);    // 16 MB [b][n][64]
  int*    gidx    = (int*)   (ws + 0x1110000);   // 4 MB
  float*  maxbuf  = (float*) (ws + 0x1510000);   // 8 MB [center][128]
  float*  minbuf  = (float*) (ws + 0x1D10000);   // 8 MB
  const unsigned long long WS_NEEDED = 0x2510000ULL;   // ~38.9 MB
  if (ws_size < WS_NEEDED) {
    fprintf(stderr, "[kernel] ws too small: %zu < %llu\n", ws_size, WS_NEEDED);
    return;
  }
  float* cA1 = coef + 0 * 128, *cC1 = coef + 1 * 128;
  float* cA2 = coef + 2 * 128, *cC2 = coef + 3 * 128;
  float* cA3 = coef + 4 * 128, *cC3 = coef + 5 * 128;

  float* out_newpc = (float*)d_out;
  float* out_feat  = (float*)d_out + (size_t)BATCH * 3 * MCTR;

  hipMemsetAsync(statsR, 0, 6 * NSLOT * 256 * sizeof(float), stream);
  prep_kernel<<<34, 256, 0, stream>>>(Wp[0][0], Wp[0][1], Wp[0][2],
                                      Wp[1][0], Wp[1][1], Wp[1][2], wt);
  prep_frag<<<120, 256, 0, stream>>>(Wp[0][1], Wp[0][2], Wp[1][1], Wp[1][2], wf);
  fps_kernel<<<BATCH, 512, 0, stream>>>(pc, samp);
  newpc_kernel<<<(BATCH * 3 * MCTR) / 256, 256, 0, stream>>>(pc, samp, out_newpc);

  const int LSTRIDE = NSLOT * 256;

  { // ---- scale 0: r=0.1, K=32, C2=64 ----
    const int P = BM * 32;   // 524288
    float* st1 = statsR + 0 * LSTRIDE, *st2 = statsR + 1 * LSTRIDE, *st3 = statsR + 2 * LSTRIDE;
    u_kernel<<<256, 256, 0, stream>>>(feat, wt + 0, bp[0][0], U);
    ballq_kernel<32><<<BM / 4, 256, 0, stream>>>(pc, out_newpc, gidx, (float)(0.1 * 0.1));
    l1_pass<32><<<P / 128, 128, 0, stream>>>(U, pc, out_newpc, gidx, wt + 4096, st1);
    finalize_kernel<<<1, 128, 0, stream>>>(st1, gp[0][0], bep[0][0], 1.0f / P, cA1, cC1, 64);
    mfma_pass<32, 64, 2><<<P / 256, 256, 0, stream>>>(U, pc, out_newpc, gidx,
        wt + 4096, wf + 0, wf + 4096, bp[0][1], bp[0][2],
        cA1, cC1, nullptr, nullptr, st2, nullptr, nullptr);
    finalize_kernel<<<1, 128, 0, stream>>>(st2, gp[0][1], bep[0][1], 1.0f / P, cA2, cC2, 64);
    mfma_pass<32, 64, 3><<<P / 256, 256, 0, stream>>>(U, pc, out_newpc, gidx,
        wt + 4096, wf + 0, wf + 4096, bp[0][1], bp[0][2],
        cA1, cC1, cA2, cC2, st3, maxbuf, minbuf);
    finalize_kernel<<<1, 128, 0, stream>>>(st3, gp[0][2], bep[0][2], 1.0f / P, cA3, cC3, 128);
    outwrite_kernel<<<BM / 64, 256, 0, stream>>>(maxbuf, minbuf, cA3, cC3, out_feat, 0);
  }

  { // ---- scale 1: r=0.2, K=64, C2=96 ----
    const int P = BM * 64;   // 1048576
    float* st1 = statsR + 3 * LSTRIDE, *st2 = statsR + 4 * LSTRIDE, *st3 = statsR + 5 * LSTRIDE;
    u_kernel<<<256, 256, 0, stream>>>(feat, wt + 16576, bp[1][0], U);
    ballq_kernel<64><<<BM / 4, 256, 0, stream>>>(pc, out_newpc, gidx, (float)(0.2 * 0.2));
    l1_pass<64><<<P / 128, 128, 0, stream>>>(U, pc, out_newpc, gidx, wt + 20672, st1);
    finalize_kernel<<<1, 128, 0, stream>>>(st1, gp[1][0], bep[1][0], 1.0f / P, cA1, cC1, 64);
    mfma_pass<64, 96, 2><<<P / 256, 256, 0, stream>>>(U, pc, out_newpc, gidx,
        wt + 20672, wf + 12288, wf + 18432, bp[1][1], bp[1][2],
        cA1, cC1, nullptr, nullptr, st2, nullptr, nullptr);
    finalize_kernel<<<1, 128, 0, stream>>>(st2, gp[1][1], bep[1][1], 1.0f / P, cA2, cC2, 96);
    mfma_pass<64, 96, 3><<<P / 256, 256, 0, stream>>>(U, pc, out_newpc, gidx,
        wt + 20672, wf + 12288, wf + 18432, bp[1][1], bp[1][2],
        cA1, cC1, cA2, cC2, st3, maxbuf, minbuf);
    finalize_kernel<<<1, 128, 0, stream>>>(st3, gp[1][2], bep[1][2], 1.0f / P, cA3, cC3, 128);
    outwrite_kernel<<<BM / 64, 256, 0, stream>>>(maxbuf, minbuf, cA3, cC3, out_feat, 128);
  }
}

// Round 7
// 1422.222 us; speedup vs baseline: 1.3205x; 1.3205x over previous
//
#include <hip/hip_runtime.h>
#include <cstdio>
#include <cstdint>

// PointNet++ SA module, MI355X. Recompute pipeline; layers 2/3 on MFMA (bf16).
// B=16, N=4096, M=1024; scale0: r=0.1,K=32,[67,64,64,128]; scale1: r=0.2,K=64,[67,64,96,128]

constexpr int BATCH = 16, NPTS = 4096, MCTR = 1024;
constexpr int BM = BATCH * MCTR;   // 16384 centers
constexpr int NSLOT = 32;          // stats contention-spreading slots

typedef short bf16x8 __attribute__((ext_vector_type(8)));
typedef float f32x4  __attribute__((ext_vector_type(4)));

__device__ __forceinline__ ushort f2bf(float f) {
  uint32_t u = __float_as_uint(f);
  u += 0x7fffu + ((u >> 16) & 1u);   // RNE
  return (ushort)(u >> 16);
}
__device__ __forceinline__ uint32_t packbf(float a, float b) {
  return (uint32_t)f2bf(a) | ((uint32_t)f2bf(b) << 16);
}
__device__ __forceinline__ unsigned long long umax64(unsigned long long a,
                                                     unsigned long long b) {
  return (a > b) ? a : b;
}

// DPP-based max over 16-lane groups: xor1, xor2 (quad_perm), ror4, ror8 (row).
// Rotation stages are valid for commutative max-reduce; after 4 stages every
// lane in a 16-group holds the group max. Register-speed, no LDS shuffles.
template <int CTRL>
__device__ __forceinline__ unsigned long long dpp16_max(unsigned long long k) {
  int lo = (int)(uint32_t)k, hi = (int)(uint32_t)(k >> 32);
  uint32_t plo = (uint32_t)__builtin_amdgcn_update_dpp(0, lo, CTRL, 0xf, 0xf, false);
  uint32_t phi = (uint32_t)__builtin_amdgcn_update_dpp(0, hi, CTRL, 0xf, 0xf, false);
  unsigned long long pk = ((unsigned long long)phi << 32) | plo;
  return (pk > k) ? pk : k;
}

// ---------------- farthest point sampling (+ fused newpc write) ----------------
// One block (256 thr) per batch, 16 pts/thread in regs. Per iter: centroid LDS
// fetch -> 16-pt update -> 4-stage DPP reduce -> 16 keys to LDS -> ONE barrier
// -> broadcast b128 readback + max tree. Distance arithmetic bit-exact vs ref.
__global__ __launch_bounds__(256) void fps_kernel(const float* __restrict__ pc,
                                                  int* __restrict__ samp,
                                                  float* __restrict__ newpc_out) {
  int b = blockIdx.x, t = threadIdx.x;
  int lane = t & 63, w = t >> 6;
  const float* px = pc + (size_t)b * 3 * NPTS;
  __shared__ float lX[NPTS], lY[NPTS], lZ[NPTS];
  __shared__ __align__(16) unsigned long long wkey[2][16];
  float X[16], Y[16], Z[16], D[16];
#pragma unroll
  for (int j = 0; j < 16; j++) {
    int p = t + 256 * j;
    float x = px[p], y = px[NPTS + p], z = px[2 * NPTS + p];
    X[j] = x; Y[j] = y; Z[j] = z; D[j] = 1e10f;
    lX[p] = x; lY[p] = y; lZ[p] = z;
  }
  __syncthreads();
  if (t == 0) samp[b * MCTR] = 0;
  float* npc = newpc_out + (size_t)b * 3 * MCTR;
  int far = 0;
  for (int it = 1; it < MCTR; it++) {
    float cx = lX[far], cy = lY[far], cz = lZ[far];
    if (t == 0) {   // newpc for sample (it-1): exactly the coords being used now
      npc[it - 1] = cx; npc[MCTR + it - 1] = cy; npc[2 * MCTR + it - 1] = cz;
    }
    float bv = -1.0f; int bi = 0;
#pragma unroll
    for (int j = 0; j < 16; j++) {
      float dx = __fsub_rn(X[j], cx), dy = __fsub_rn(Y[j], cy), dz = __fsub_rn(Z[j], cz);
      float d = __fadd_rn(__fadd_rn(__fmul_rn(dx, dx), __fmul_rn(dy, dy)), __fmul_rn(dz, dz));
      float dm = fminf(D[j], d);
      D[j] = dm;
      bool g = dm > bv;               // ascending j => first-index within thread
      bv = g ? dm : bv; bi = g ? t + 256 * j : bi;
    }
    // d >= 0 => sign clear => uint order == float order; ~idx => first-index ties
    unsigned long long key =
        ((unsigned long long)__float_as_uint(bv) << 32) | (unsigned)(~bi);
    key = dpp16_max<0xB1>(key);    // quad_perm [1,0,3,2]  (xor 1)
    key = dpp16_max<0x4E>(key);    // quad_perm [2,3,0,1]  (xor 2)
    key = dpp16_max<0x124>(key);   // row_ror:4
    key = dpp16_max<0x128>(key);   // row_ror:8
    if ((lane & 15) == 0) wkey[it & 1][w * 4 + (lane >> 4)] = key;
    __syncthreads();
    const ulonglong2* kp = (const ulonglong2*)wkey[it & 1];
    unsigned long long kk[8];
#pragma unroll
    for (int i = 0; i < 8; i++) { ulonglong2 v = kp[i]; kk[i] = umax64(v.x, v.y); }
#pragma unroll
    for (int s = 4; s; s >>= 1)
#pragma unroll
      for (int i = 0; i < s; i++) kk[i] = umax64(kk[i], kk[i + s]);
    far = (int)(~(unsigned)kk[0]);
    if (t == 0) samp[b * MCTR + it] = far;
  }
  if (t == 0) {   // last sample's coords
    npc[MCTR - 1] = lX[far]; npc[2 * MCTR - 1] = lY[far]; npc[3 * MCTR - 1] = lZ[far];
  }
}

// ---------------- ball query: wave per center, ballot-ranked first-K ----------------
template <int K>
__global__ __launch_bounds__(256) void ballq_kernel(const float* __restrict__ pc,
                                                    const float* __restrict__ newpc,
                                                    int* __restrict__ gidx, float r2) {
  int lane = threadIdx.x & 63;
  int wave = threadIdx.x >> 6;
  int center = blockIdx.x * 4 + wave;
  int b = center >> 10, m = center & 1023;
  const float* nb = newpc + (size_t)b * 3 * MCTR + m;
  float cx = nb[0], cy = nb[MCTR], cz = nb[2 * MCTR];
  const float* px = pc + (size_t)b * 3 * NPTS;
  int cnt = 0;
  int firstn = 0x7fffffff;
  for (int chunk = 0; chunk < NPTS / 64 && cnt < K; chunk++) {
    int n = chunk * 64 + lane;
    float dx = __fsub_rn(cx, px[n]);
    float dy = __fsub_rn(cy, px[NPTS + n]);
    float dz = __fsub_rn(cz, px[2 * NPTS + n]);
    float d2 = __fadd_rn(__fadd_rn(__fmul_rn(dx, dx), __fmul_rn(dy, dy)), __fmul_rn(dz, dz));
    bool in = d2 < r2;
    unsigned long long ball = __ballot(in);
    int pos = cnt + (int)__popcll(ball & ((1ull << lane) - 1ull));
    if (in && pos < K) gidx[(size_t)center * K + pos] = n;
    if (in && pos == 0) firstn = n;
    cnt += (int)__popcll(ball);
  }
#pragma unroll
  for (int off = 32; off; off >>= 1) firstn = min(firstn, __shfl_xor(firstn, off));
  if (lane < K && lane >= cnt) gidx[(size_t)center * K + lane] = firstn;
}

// ---------------- weight prep: fp32 transposes + bf16 MFMA A-fragments ----------------
// wt (float): WtF0@0(4096) Wt1x0@4096(192) WtF1@4288(4096) Wt1x1@8384(192)
// wf (ushort): W2f0@0(4096) W3f0@4096(8192) W2f1@12288(6144) W3f1@18432(12288)
__global__ __launch_bounds__(256) void prep_all(const float* __restrict__ W00,
                                                const float* __restrict__ W01,
                                                const float* __restrict__ W02,
                                                const float* __restrict__ W10,
                                                const float* __restrict__ W11,
                                                const float* __restrict__ W12,
                                                float* __restrict__ wt,
                                                ushort* __restrict__ wf) {
  int e = blockIdx.x * 256 + threadIdx.x;
  if (e < 4096) { wt[e] = W00[(e & 63) * 67 + 3 + (e >> 6)]; return; }
  if (e < 4288) { int r = e - 4096; wt[e] = W00[(r & 63) * 67 + (r >> 6)]; return; }
  if (e < 8384) { int r = e - 4288; wt[e] = W10[(r & 63) * 67 + 3 + (r >> 6)]; return; }
  if (e < 8576) { int r = e - 8384; wt[e] = W10[(r & 63) * 67 + (r >> 6)]; return; }
  int e2 = e - 8576;
  if (e2 >= 30720) return;
  const float* W; int CIN, MT, off;
  if (e2 < 4096)       { W = W01; CIN = 64; MT = 4; off = 0; }
  else if (e2 < 12288) { W = W02; CIN = 64; MT = 8; off = 4096; }
  else if (e2 < 18432) { W = W11; CIN = 64; MT = 6; off = 12288; }
  else                 { W = W12; CIN = 96; MT = 8; off = 18432; }
  int r = e2 - off;
  int j = r & 7, lane = (r >> 3) & 63, fm = r >> 9;
  int kc = fm / MT, mt = fm % MT;
  int out_ch = mt * 16 + (lane & 15);
  int in_ch  = kc * 32 + (lane >> 4) * 8 + j;
  wf[e2] = f2bf(W[out_ch * CIN + in_ch]);
}

// ---------------- U = bf16(W_feat . feat + b1), layout [b][n][64] ----------------
__global__ __launch_bounds__(256) void u_kernel(const float* __restrict__ feat,
                                                const float* __restrict__ WtF,
                                                const float* __restrict__ b1,
                                                ushort* __restrict__ Ub) {
  int gid = blockIdx.x * 256 + threadIdx.x;
  int b = gid >> 12, n = gid & 4095;
  float acc[64];
#pragma unroll
  for (int o = 0; o < 64; o++) acc[o] = b1[o];
  const float* fb = feat + (size_t)b * 64 * NPTS + n;
  for (int c = 0; c < 64; c++) {
    float x = fb[(size_t)c * NPTS];
    const float* wc = WtF + c * 64;
#pragma unroll
    for (int o = 0; o < 64; o++) acc[o] = fmaf(wc[o], x, acc[o]);
  }
  uint4* o4 = (uint4*)(Ub + (size_t)gid * 64);
#pragma unroll
  for (int qq = 0; qq < 8; qq++)
    o4[qq] = make_uint4(packbf(acc[8*qq+0], acc[8*qq+1]), packbf(acc[8*qq+2], acc[8*qq+3]),
                        packbf(acc[8*qq+4], acc[8*qq+5]), packbf(acc[8*qq+6], acc[8*qq+7]));
}

// ---------------- bf16 U gather + layer1 (shared by l1_pass / mfma_pass) ----------------
__device__ __forceinline__ void layer1_compute(const ushort* __restrict__ Ub,
                                               const float* __restrict__ pc,
                                               const float* __restrict__ newpc,
                                               const float* __restrict__ Wt1,
                                               int b, int m, int idx, float* v1) {
  float dx = pc[((size_t)b * 3 + 0) * NPTS + idx] - newpc[((size_t)b * 3 + 0) * MCTR + m];
  float dy = pc[((size_t)b * 3 + 1) * NPTS + idx] - newpc[((size_t)b * 3 + 1) * MCTR + m];
  float dz = pc[((size_t)b * 3 + 2) * NPTS + idx] - newpc[((size_t)b * 3 + 2) * MCTR + m];
  const uint4* u4 = (const uint4*)(Ub + (size_t)((b << 12) + idx) * 64);
#pragma unroll
  for (int qq = 0; qq < 8; qq++) {
    uint4 u = u4[qq];
    v1[8*qq+0] = __uint_as_float(u.x << 16);
    v1[8*qq+1] = __uint_as_float(u.x & 0xffff0000u);
    v1[8*qq+2] = __uint_as_float(u.y << 16);
    v1[8*qq+3] = __uint_as_float(u.y & 0xffff0000u);
    v1[8*qq+4] = __uint_as_float(u.z << 16);
    v1[8*qq+5] = __uint_as_float(u.z & 0xffff0000u);
    v1[8*qq+6] = __uint_as_float(u.w << 16);
    v1[8*qq+7] = __uint_as_float(u.w & 0xffff0000u);
  }
#pragma unroll
  for (int o = 0; o < 64; o++) v1[o] = fmaf(Wt1[o], dx, v1[o]);
#pragma unroll
  for (int o = 0; o < 64; o++) v1[o] = fmaf(Wt1[64 + o], dy, v1[o]);
#pragma unroll
  for (int o = 0; o < 64; o++) v1[o] = fmaf(Wt1[128 + o], dz, v1[o]);
}

// ---------------- layer-1 stats pass (VALU; cheap) ----------------
template <int K>
__device__ __forceinline__ void wave_reduce32(const float* vals, float* tile, int t,
                                              float* swrow, int co) {
  float* myrow = tile + t * 32;
  int rsw = t & 31;
#pragma unroll
  for (int o = 0; o < 32; o++) myrow[o ^ rsw] = vals[o];
  __syncthreads();
  int lane = t & 63;
  int ch = lane & 31, sub = lane >> 5;
  const float* base = tile + (t & ~63) * 32;
  float s = 0.f, s2 = 0.f;
#pragma unroll
  for (int r = 0; r < 32; r++) {
    int row = sub * 32 + r;
    float v = base[row * 32 + (ch ^ (row & 31))];
    s += v; s2 = fmaf(v, v, s2);
  }
  float st = s + __shfl_xor(s, 32);
  float st2 = s2 + __shfl_xor(s2, 32);
  if (sub == 0) {
    swrow[co + ch] += st;
    swrow[128 + co + ch] += st2;
  }
  __syncthreads();
}

template <int K>
__global__ __launch_bounds__(128, 2) void l1_pass(
    const ushort* __restrict__ Ub, const float* __restrict__ pc,
    const float* __restrict__ newpc, const int* __restrict__ gidx,
    const float* __restrict__ Wt1, float* __restrict__ stats) {
  __shared__ float tile[128 * 32];
  __shared__ float sAccW[2][256];
  const int t = threadIdx.x;
  const int w = t >> 6;
  const int p = blockIdx.x * 128 + t;
  const int bm = p / K;
  const int b = bm >> 10, m = bm & 1023;
  const int idx = gidx[p];
  for (int i = t; i < 512; i += 128) ((float*)sAccW)[i] = 0.f;

  float v1[64];
  layer1_compute(Ub, pc, newpc, Wt1, b, m, idx, v1);

  wave_reduce32<K>(v1,      tile, t, sAccW[w], 0);
  wave_reduce32<K>(v1 + 32, tile, t, sAccW[w], 32);

  __syncthreads();
  float* dst = stats + (size_t)(blockIdx.x & (NSLOT - 1)) * 128;
  for (int i = t; i < 64; i += 128) {
    atomicAdd(&dst[i],      sAccW[0][i]       + sAccW[1][i]);
    atomicAdd(&dst[64 + i], sAccW[0][128 + i] + sAccW[1][128 + i]);
  }
}

// ---------------- MFMA MLP pass: layer1 (VALU) -> layer2[/3] (MFMA) ----------------
// NL=2: stats of pre-BN layer2.  NL=3: stats of pre-BN layer3 + per-center max/min.
// All LDS regions are per-wave: no block barrier until the final stats flush.
template <int K, int C2, int NL>
__global__ __launch_bounds__(256, 2) void mfma_pass(
    const ushort* __restrict__ Ub, const float* __restrict__ pc,
    const float* __restrict__ newpc, const int* __restrict__ gidx,
    const float* __restrict__ Wt1,
    const ushort* __restrict__ W2f, const ushort* __restrict__ W3f,
    const float* __restrict__ b2, const float* __restrict__ b3,
    const float* __restrict__ cA1, const float* __restrict__ cC1,
    const float* __restrict__ cA2, const float* __restrict__ cC2,
    float* __restrict__ stats, float* __restrict__ maxbuf, float* __restrict__ minbuf) {
  constexpr int MT2 = C2 / 16, KC3 = C2 / 32;
  constexpr int CLs = (NL == 2) ? C2 : 128;
  constexpr int SSTR = CLs + 4;                       // scratch row stride (ushorts)
  __shared__ __align__(16) ushort x1f[4][2][4][64][8];         // 32 KB, B-frag order
  __shared__ __align__(16) ushort x2f[(NL == 3) ? 4 : 1][KC3][4][16][8];
  __shared__ __align__(16) ushort x3s[4][16][SSTR];            // pre-BN scratch rows
  __shared__ float sAccW[4][256];

  const int t = threadIdx.x, w = t >> 6, lane = t & 63;
  const int q = lane >> 4, n = lane & 15;
  const int p = blockIdx.x * 256 + t;
  const int bm = p / K;
  const int b = bm >> 10, m = bm & 1023;
  const int idx = gidx[p];

  // ---- layer1 per-thread (position = t) ----
  {
    float v1[64];
    layer1_compute(Ub, pc, newpc, Wt1, b, m, idx, v1);
    // bn1relu -> x1f B-frag rows (ch = kc*32 + q*8 + j), own 16B slot per thread
    int nw = t & 63;
#pragma unroll
    for (int g = 0; g < 8; g++) {
      uint32_t d0, d1, d2, d3;
      int c = g * 8;
      d0 = packbf(fmaxf(0.f, fmaf(cA1[c+0], v1[c+0], cC1[c+0])),
                  fmaxf(0.f, fmaf(cA1[c+1], v1[c+1], cC1[c+1])));
      d1 = packbf(fmaxf(0.f, fmaf(cA1[c+2], v1[c+2], cC1[c+2])),
                  fmaxf(0.f, fmaf(cA1[c+3], v1[c+3], cC1[c+3])));
      d2 = packbf(fmaxf(0.f, fmaf(cA1[c+4], v1[c+4], cC1[c+4])),
                  fmaxf(0.f, fmaf(cA1[c+5], v1[c+5], cC1[c+5])));
      d3 = packbf(fmaxf(0.f, fmaf(cA1[c+6], v1[c+6], cC1[c+6])),
                  fmaxf(0.f, fmaf(cA1[c+7], v1[c+7], cC1[c+7])));
      *(uint4*)&x1f[w][g >> 2][g & 3][nw][0] = make_uint4(d0, d1, d2, d3);
    }
  }
  asm volatile("s_waitcnt lgkmcnt(0)" ::: "memory");

  // ---- preload A-fragments into registers ----
  bf16x8 A2[2 * MT2];
#pragma unroll
  for (int i = 0; i < 2 * MT2; i++) A2[i] = *(const bf16x8*)(W2f + (i * 64 + lane) * 8);
  bf16x8 A3[(NL == 3) ? KC3 * 8 : 1];
  if (NL == 3) {
#pragma unroll
    for (int i = 0; i < KC3 * 8; i++) A3[i] = *(const bf16x8*)(W3f + (i * 64 + lane) * 8);
  }

  float sS0 = 0.f, sS1 = 0.f, sS20 = 0.f, sS21 = 0.f;
  float mx0 = -3.4e38f, mx1 = -3.4e38f, mn0 = 3.4e38f, mn1 = 3.4e38f;

#pragma unroll
  for (int tl = 0; tl < 4; tl++) {
    // layer2 MFMA
    bf16x8 bf2[2];
#pragma unroll
    for (int kc = 0; kc < 2; kc++)
      bf2[kc] = *(const bf16x8*)&x1f[w][kc][q][tl * 16 + n][0];
    f32x4 acc2[MT2];
#pragma unroll
    for (int mt = 0; mt < MT2; mt++) acc2[mt] = *(const f32x4*)(b2 + mt * 16 + q * 4);
#pragma unroll
    for (int kc = 0; kc < 2; kc++)
#pragma unroll
      for (int mt = 0; mt < MT2; mt++)
        acc2[mt] = __builtin_amdgcn_mfma_f32_16x16x32_bf16(A2[kc * MT2 + mt], bf2[kc],
                                                           acc2[mt], 0, 0, 0);
    if (NL == 2) {
      // pre-BN layer2 -> scratch
#pragma unroll
      for (int mt = 0; mt < MT2; mt++) {
        int ch0 = mt * 16 + q * 4;
        *(uint2*)&x3s[w][n][ch0] = make_uint2(packbf(acc2[mt][0], acc2[mt][1]),
                                              packbf(acc2[mt][2], acc2[mt][3]));
      }
    } else {
      // bn2relu -> x2f B-frag rows
#pragma unroll
      for (int mt = 0; mt < MT2; mt++) {
        int ch0 = mt * 16 + q * 4;
        f32x4 ca = *(const f32x4*)(cA2 + ch0);
        f32x4 cc = *(const f32x4*)(cC2 + ch0);
        float r0 = fmaxf(0.f, fmaf(ca[0], acc2[mt][0], cc[0]));
        float r1 = fmaxf(0.f, fmaf(ca[1], acc2[mt][1], cc[1]));
        float r2 = fmaxf(0.f, fmaf(ca[2], acc2[mt][2], cc[2]));
        float r3 = fmaxf(0.f, fmaf(ca[3], acc2[mt][3], cc[3]));
        int kc2 = ch0 >> 5, q2 = (ch0 >> 3) & 3, j0 = ch0 & 7;
        *(uint2*)&x2f[w][kc2][q2][n][j0] = make_uint2(packbf(r0, r1), packbf(r2, r3));
      }
      asm volatile("s_waitcnt lgkmcnt(0)" ::: "memory");
      // layer3 MFMA
      f32x4 acc3[8];
#pragma unroll
      for (int mt = 0; mt < 8; mt++) acc3[mt] = *(const f32x4*)(b3 + mt * 16 + q * 4);
#pragma unroll
      for (int kc = 0; kc < KC3; kc++) {
        bf16x8 bf3 = *(const bf16x8*)&x2f[w][kc][q][n][0];
#pragma unroll
        for (int mt = 0; mt < 8; mt++)
          acc3[mt] = __builtin_amdgcn_mfma_f32_16x16x32_bf16(A3[kc * 8 + mt], bf3,
                                                             acc3[mt], 0, 0, 0);
      }
      // pre-BN layer3 -> scratch
#pragma unroll
      for (int mt = 0; mt < 8; mt++) {
        int ch0 = mt * 16 + q * 4;
        *(uint2*)&x3s[w][n][ch0] = make_uint2(packbf(acc3[mt][0], acc3[mt][1]),
                                              packbf(acc3[mt][2], acc3[mt][3]));
      }
    }
    asm volatile("s_waitcnt lgkmcnt(0)" ::: "memory");
    // readback reduce: this lane owns channels (2*lane, 2*lane+1)
    if (2 * lane < CLs) {
#pragma unroll
      for (int pos = 0; pos < 16; pos++) {
        uint32_t u = *(const uint32_t*)&x3s[w][pos][2 * lane];
        float v0 = __uint_as_float(u << 16);
        float v1v = __uint_as_float(u & 0xffff0000u);
        sS0 += v0;  sS20 = fmaf(v0, v0, sS20);
        sS1 += v1v; sS21 = fmaf(v1v, v1v, sS21);
        if (NL == 3) {
          mx0 = fmaxf(mx0, v0);  mn0 = fminf(mn0, v0);
          mx1 = fmaxf(mx1, v1v); mn1 = fminf(mn1, v1v);
        }
      }
    }
    if (NL == 3) {
      bool fl = (K == 64) ? (tl == 3) : ((tl & 1) == 1);
      if (fl) {
        int center = (K == 64) ? (blockIdx.x * 4 + w)
                               : (blockIdx.x * 8 + w * 2 + (tl >> 1));
        *(float2*)&maxbuf[(size_t)center * 128 + 2 * lane] = make_float2(mx0, mx1);
        *(float2*)&minbuf[(size_t)center * 128 + 2 * lane] = make_float2(mn0, mn1);
        mx0 = mx1 = -3.4e38f; mn0 = mn1 = 3.4e38f;
      }
    }
    asm volatile("s_waitcnt lgkmcnt(0)" ::: "memory");   // scratch reuse next tl
  }

  // ---- stats: per-wave LDS row, then one slotted flush per block ----
  {
    int ch = 2 * lane;
    if (ch < CLs) {
      sAccW[w][ch] = sS0;        sAccW[w][ch + 1] = sS1;
      sAccW[w][CLs + ch] = sS20; sAccW[w][CLs + ch + 1] = sS21;
    }
  }
  __syncthreads();
  float* dst = stats + (size_t)(blockIdx.x & (NSLOT - 1)) * (2 * CLs);
  for (int i = t; i < 2 * CLs; i += 256)
    atomicAdd(&dst[i], sAccW[0][i] + sAccW[1][i] + sAccW[2][i] + sAccW[3][i]);
}

// ---------------- BN coeffs from slotted stats, both scales in one launch ----------------
__global__ void finalize2_kernel(const float* __restrict__ st0, const float* __restrict__ g0,
                                 const float* __restrict__ be0, float invP0,
                                 float* __restrict__ cAo0, float* __restrict__ cCo0, int C0,
                                 const float* __restrict__ st1, const float* __restrict__ g1,
                                 const float* __restrict__ be1, float invP1,
                                 float* __restrict__ cAo1, float* __restrict__ cCo1, int C1) {
  const float* st = blockIdx.x ? st1 : st0;
  const float* g  = blockIdx.x ? g1  : g0;
  const float* be = blockIdx.x ? be1 : be0;
  float invP = blockIdx.x ? invP1 : invP0;
  float* cA = blockIdx.x ? cAo1 : cAo0;
  float* cC = blockIdx.x ? cCo1 : cCo0;
  int C = blockIdx.x ? C1 : C0;
  int t = threadIdx.x;
  if (t < C) {
    float s = 0.f, s2 = 0.f;
    for (int sl = 0; sl < NSLOT; sl++) {
      s  += st[sl * 2 * C + t];
      s2 += st[sl * 2 * C + C + t];
    }
    float mu = s * invP;
    float var = fmaf(s2, invP, -(mu * mu));
    float a = g[t] / sqrtf(var + 1e-5f);
    cA[t] = a;
    cC[t] = fmaf(-a, mu, be[t]);
  }
}

// ---------------- final output: affine(max/min by sign) + relu, transposed write ----------------
__global__ __launch_bounds__(256) void outwrite_kernel(const float* __restrict__ maxbuf,
                                                       const float* __restrict__ minbuf,
                                                       const float* __restrict__ cA3,
                                                       const float* __restrict__ cC3,
                                                       float* __restrict__ out_feat, int chOff) {
  __shared__ float tile[64 * 130];
  int c0 = blockIdx.x * 64;
  int t = threadIdx.x;
#pragma unroll
  for (int i = 0; i < 32; i++) {
    int e = i * 256 + t;
    int lc = e >> 7, o = e & 127;
    float a = cA3[o];
    float v = (a >= 0.f) ? fmaf(a, maxbuf[(size_t)(c0 + lc) * 128 + o], cC3[o])
                         : fmaf(a, minbuf[(size_t)(c0 + lc) * 128 + o], cC3[o]);
    tile[lc * 130 + o] = fmaxf(v, 0.f);
  }
  __syncthreads();
  int b = c0 >> 10, m0 = c0 & 1023;
#pragma unroll
  for (int j = 0; j < 32; j++) {
    int e = j * 256 + t;
    int lm = e & 63, o = e >> 6;
    out_feat[((size_t)(b * 256 + chOff + o)) * MCTR + m0 + lm] = tile[lm * 130 + o];
  }
}

// ======================= host launch =======================
extern "C" void kernel_launch(void* const* d_in, const int* in_sizes, int n_in,
                              void* d_out, int out_size, void* d_ws, size_t ws_size,
                              hipStream_t stream) {
  (void)in_sizes; (void)n_in; (void)out_size;
  const float* pc   = (const float*)d_in[0];
  const float* feat = (const float*)d_in[1];
  const float *Wp[2][3], *bp[2][3], *gp[2][3], *bep[2][3];
  for (int s = 0; s < 2; s++)
    for (int l = 0; l < 3; l++) {
      int base = 2 + (s * 3 + l) * 4;
      Wp[s][l]  = (const float*)d_in[base + 0];
      bp[s][l]  = (const float*)d_in[base + 1];
      gp[s][l]  = (const float*)d_in[base + 2];
      bep[s][l] = (const float*)d_in[base + 3];
    }

  char* ws = (char*)d_ws;
  int*    samp    = (int*)   (ws + 0x0);         // 64 KB
  float*  statsR  = (float*) (ws + 0x10000);     // 6 x NSLOT x 256 f32 = 192 KB
  float*  coef    = (float*) (ws + 0x40000);     // 2 scales x 768 f32
  float*  wt      = (float*) (ws + 0x42000);     // 8576 f32
  ushort* wf      = (ushort*)(ws + 0x50000);     // 60 KB bf16 A-frags
  ushort* Ub0     = (ushort*)(ws + 0x100000);    // 8 MB [b][n][64] bf16
  ushort* Ub1     = (ushort*)(ws + 0x900000);    // 8 MB
  int*    gidx0   = (int*)   (ws + 0x1100000);   // 2 MB
  int*    gidx1   = (int*)   (ws + 0x1300000);   // 4 MB
  float*  maxbuf  = (float*) (ws + 0x1700000);   // 8 MB [center][128]
  float*  minbuf  = (float*) (ws + 0x1F00000);   // 8 MB
  const unsigned long long WS_NEEDED = 0x2700000ULL;   // ~39.3 MB
  if (ws_size < WS_NEEDED) {
    fprintf(stderr, "[kernel] ws too small: %zu < %llu\n", ws_size, WS_NEEDED);
    return;
  }
  float* cf0 = coef, *cf1 = coef + 768;
  // per scale: cA1@0 cC1@128 cA2@256 cC2@384 cA3@512 cC3@640

  float* out_newpc = (float*)d_out;
  float* out_feat  = (float*)d_out + (size_t)BATCH * 3 * MCTR;

  const int P0 = BM * 32, P1 = BM * 64;
  const int LSTRIDE = NSLOT * 256;
  float* st10 = statsR + 0 * LSTRIDE, *st20 = statsR + 1 * LSTRIDE, *st30 = statsR + 2 * LSTRIDE;
  float* st11 = statsR + 3 * LSTRIDE, *st21 = statsR + 4 * LSTRIDE, *st31 = statsR + 5 * LSTRIDE;

  hipMemsetAsync(statsR, 0, 6 * NSLOT * 256 * sizeof(float), stream);
  prep_all<<<154, 256, 0, stream>>>(Wp[0][0], Wp[0][1], Wp[0][2],
                                    Wp[1][0], Wp[1][1], Wp[1][2], wt, wf);
  fps_kernel<<<BATCH, 256, 0, stream>>>(pc, samp, out_newpc);
  ballq_kernel<32><<<BM / 4, 256, 0, stream>>>(pc, out_newpc, gidx0, (float)(0.1 * 0.1));
  ballq_kernel<64><<<BM / 4, 256, 0, stream>>>(pc, out_newpc, gidx1, (float)(0.2 * 0.2));
  u_kernel<<<256, 256, 0, stream>>>(feat, wt + 0,    bp[0][0], Ub0);
  u_kernel<<<256, 256, 0, stream>>>(feat, wt + 4288, bp[1][0], Ub1);

  l1_pass<32><<<P0 / 128, 128, 0, stream>>>(Ub0, pc, out_newpc, gidx0, wt + 4096, st10);
  l1_pass<64><<<P1 / 128, 128, 0, stream>>>(Ub1, pc, out_newpc, gidx1, wt + 8384, st11);
  finalize2_kernel<<<2, 128, 0, stream>>>(st10, gp[0][0], bep[0][0], 1.0f / P0,
                                          cf0 + 0, cf0 + 128, 64,
                                          st11, gp[1][0], bep[1][0], 1.0f / P1,
                                          cf1 + 0, cf1 + 128, 64);

  mfma_pass<32, 64, 2><<<P0 / 256, 256, 0, stream>>>(Ub0, pc, out_newpc, gidx0,
      wt + 4096, wf + 0, wf + 4096, bp[0][1], bp[0][2],
      cf0 + 0, cf0 + 128, nullptr, nullptr, st20, nullptr, nullptr);
  mfma_pass<64, 96, 2><<<P1 / 256, 256, 0, stream>>>(Ub1, pc, out_newpc, gidx1,
      wt + 8384, wf + 12288, wf + 18432, bp[1][1], bp[1][2],
      cf1 + 0, cf1 + 128, nullptr, nullptr, st21, nullptr, nullptr);
  finalize2_kernel<<<2, 128, 0, stream>>>(st20, gp[0][1], bep[0][1], 1.0f / P0,
                                          cf0 + 256, cf0 + 384, 64,
                                          st21, gp[1][1], bep[1][1], 1.0f / P1,
                                          cf1 + 256, cf1 + 384, 96);

  mfma_pass<32, 64, 3><<<P0 / 256, 256, 0, stream>>>(Ub0, pc, out_newpc, gidx0,
      wt + 4096, wf + 0, wf + 4096, bp[0][1], bp[0][2],
      cf0 + 0, cf0 + 128, cf0 + 256, cf0 + 384, st30, maxbuf, minbuf);
  finalize2_kernel<<<1, 128, 0, stream>>>(st30, gp[0][2], bep[0][2], 1.0f / P0,
                                          cf0 + 512, cf0 + 640, 128,
                                          st30, gp[0][2], bep[0][2], 1.0f / P0,
                                          cf0 + 512, cf0 + 640, 128);
  outwrite_kernel<<<BM / 64, 256, 0, stream>>>(maxbuf, minbuf, cf0 + 512, cf0 + 640,
                                               out_feat, 0);

  mfma_pass<64, 96, 3><<<P1 / 256, 256, 0, stream>>>(Ub1, pc, out_newpc, gidx1,
      wt + 8384, wf + 12288, wf + 18432, bp[1][1], bp[1][2],
      cf1 + 0, cf1 + 128, cf1 + 256, cf1 + 384, st31, maxbuf, minbuf);
  finalize2_kernel<<<1, 128, 0, stream>>>(st31, gp[1][2], bep[1][2], 1.0f / P1,
                                          cf1 + 512, cf1 + 640, 128,
                                          st31, gp[1][2], bep[1][2], 1.0f / P1,
                                          cf1 + 512, cf1 + 640, 128);
  outwrite_kernel<<<BM / 64, 256, 0, stream>>>(maxbuf, minbuf, cf1 + 512, cf1 + 640,
                                               out_feat, 128);
}